// Round 5
// baseline (336.070 us; speedup 1.0000x reference)
//
#include <hip/hip_runtime.h>
#include <hip/hip_bf16.h>

#define B_  8
#define F_  256
#define N_  4096
#define BN  16
#define TPB 4            // tiles per block
#define GRID 512         // 2 blocks/CU
#define THREADS 512
#define TSTRIDE 1088     // (64+4 pad) units * 16 B per (ch,k) sub-tile
#define BUFU (24 * 68)   // uint4 units per buffer

typedef __attribute__((ext_vector_type(8))) short short8;
typedef __attribute__((ext_vector_type(4))) float f32x4;
typedef __attribute__((ext_vector_type(4))) unsigned short us4;

__device__ inline unsigned short f2bf(float f) {
    union { float f; unsigned int u; } c; c.f = f;
    unsigned int u = c.u;
    unsigned int r = u + 0x7FFFu + ((u >> 16) & 1u);   // RNE
    return (unsigned short)(r >> 16);
}
__device__ inline unsigned int pack2(float a, float b) {
    return (unsigned int)f2bf(a) | ((unsigned int)f2bf(b) << 16);
}
__device__ inline float bf2f(unsigned short h) {
    union { unsigned int u; float f; } c; c.u = ((unsigned int)h) << 16;
    return c.f;
}

// ---- pre-kernel: W1,W2 fp32 -> bf16 Wb[2][256][256] in d_ws ----
__global__ void wconv_kernel(const float* __restrict__ W1,
                             const float* __restrict__ W2,
                             unsigned short* __restrict__ Wb) {
    int t = blockIdx.x * blockDim.x + threadIdx.x;   // 0..16383
    int e = t * 8;
    const float* src = (e & 65536) ? W2 : W1;
    int rem = e & 65535;
    float4 a = *(const float4*)(src + rem);
    float4 b = *(const float4*)(src + rem + 4);
    short8 o;
    o[0] = (short)f2bf(a.x); o[1] = (short)f2bf(a.y);
    o[2] = (short)f2bf(a.z); o[3] = (short)f2bf(a.w);
    o[4] = (short)f2bf(b.x); o[5] = (short)f2bf(b.y);
    o[6] = (short)f2bf(b.z); o[7] = (short)f2bf(b.w);
    *(short8*)(Wb + e) = o;
}

__device__ inline void load_tile(const float* __restrict__ xb, int fp, int q,
                                 float4* ra, float4* rb) {
    #pragma unroll
    for (int it = 0; it < 3; it++) {
        const float* p = xb + (size_t)(6 * fp + it) * N_ + q * 4;
        ra[it] = *(const float4*)p;
        rb[it] = *(const float4*)(p + 3 * N_);
    }
}

__device__ inline void write_tile(char* __restrict__ buf, int ch_s, int qw,
                                  int dd, int q, const float4* ra, const float4* rb) {
    #pragma unroll
    for (int it = 0; it < 3; it++) {
        char* tbase = buf + (ch_s * 3 + it) * TSTRIDE + dd * 4;
        const float* fa = (const float*)&ra[it];
        const float* fb = (const float*)&rb[it];
        #pragma unroll
        for (int dn = 0; dn < 4; dn++) {
            int uu = qw * 16 + q * 4 + dn;
            *(unsigned int*)(tbase + (uu + qw) * 16) = pack2(fa[dn], fb[dn]);
        }
    }
}

__global__ __launch_bounds__(THREADS, 4) void lie_fused_kernel(
    const float* __restrict__ x, const float* __restrict__ M1,
    const float* __restrict__ M2, const unsigned short* __restrict__ Wb,
    float* __restrict__ out)
{
    __shared__ uint4 Xs[2][BUFU];   // 2 x 26112 B, B-frag order, pad 1/16 units

    const int tid  = threadIdx.x;
    const int wave = tid >> 6;
    const int lane = tid & 63;
    const int c16  = lane & 15;
    const int quad = lane >> 4;

    // staging decomposition
    const int fp   = tid >> 2;        // 0..127 (f-pair)
    const int q    = tid & 3;         // n float4 index
    const int ch_s = fp >> 4;
    const int fpl  = fp & 15;
    const int qw   = fpl >> 2;
    const int dd   = fpl & 3;

    const int rdoff = (lane + (lane >> 4)) * 16;   // compute-read offset in sub-tile

    const unsigned short* wbase = Wb + (wave * 32 + c16) * 256 + quad * 8;

    float m1v[9], m2v[9];
    #pragma unroll
    for (int i = 0; i < 9; i++) { m1v[i] = M1[i]; m2v[i] = M2[i]; }

    float4 ra[3], rb[3];

    int task = blockIdx.x;
    {
        const float* xb = x + (size_t)(task >> 8) * 768 * N_ + (task & 255) * BN;
        load_tile(xb, fp, q, ra, rb);
    }

    for (int t = 0; t < TPB; t++) {
        char* buf = (char*)Xs[t & 1];

        // consume the loads issued last iteration (or prologue)
        write_tile(buf, ch_s, qw, dd, q, ra, rb);
        __syncthreads();

        const int b  = task >> 8;
        const int nt = task & 255;
        const int next = task + GRID;

        // issue next tile's loads NOW — in flight across MFMA + epilogue
        if (t < TPB - 1) {
            const float* xb = x + (size_t)(next >> 8) * 768 * N_ + (next & 255) * BN;
            load_tile(xb, fp, q, ra, rb);
        }

        f32x4 acc[2][2][3];
        #pragma unroll
        for (int wi = 0; wi < 2; wi++)
            #pragma unroll
            for (int gt = 0; gt < 2; gt++)
                #pragma unroll
                for (int k = 0; k < 3; k++)
                    acc[wi][gt][k] = (f32x4)(0.f);

        short8 a00 = *(const short8*)(wbase);
        short8 a01 = *(const short8*)(wbase + 4096);
        short8 a10 = *(const short8*)(wbase + 65536);
        short8 a11 = *(const short8*)(wbase + 69632);
        #pragma unroll
        for (int ch = 0; ch < 8; ch++) {
            short8 n00, n01, n10, n11;
            if (ch < 7) {
                n00 = *(const short8*)(wbase + (ch + 1) * 32);
                n01 = *(const short8*)(wbase + 4096 + (ch + 1) * 32);
                n10 = *(const short8*)(wbase + 65536 + (ch + 1) * 32);
                n11 = *(const short8*)(wbase + 69632 + (ch + 1) * 32);
            }
            short8 bfr[3];
            #pragma unroll
            for (int k = 0; k < 3; k++)
                bfr[k] = *(const short8*)(buf + (ch * 3 + k) * TSTRIDE + rdoff);
            #pragma unroll
            for (int k = 0; k < 3; k++) {
                acc[0][0][k] = __builtin_amdgcn_mfma_f32_16x16x32_bf16(a00, bfr[k], acc[0][0][k], 0, 0, 0);
                acc[0][1][k] = __builtin_amdgcn_mfma_f32_16x16x32_bf16(a01, bfr[k], acc[0][1][k], 0, 0, 0);
                acc[1][0][k] = __builtin_amdgcn_mfma_f32_16x16x32_bf16(a10, bfr[k], acc[1][0][k], 0, 0, 0);
                acc[1][1][k] = __builtin_amdgcn_mfma_f32_16x16x32_bf16(a11, bfr[k], acc[1][1][k], 0, 0, 0);
            }
            if (ch < 7) { a00 = n00; a01 = n01; a10 = n10; a11 = n11; }
        }

        // epilogue: rotate + cross + residual (x back from LDS)
        float* ob = out + (size_t)b * 768 * N_ + nt * BN + c16;
        #pragma unroll
        for (int gt = 0; gt < 2; gt++) {
            us4 rx[3];
            const int qp = gt * 2 + (quad >> 1);
            #pragma unroll
            for (int k = 0; k < 3; k++) {
                int uu = qp * 16 + c16;
                rx[k] = *(const us4*)(buf + (wave * 3 + k) * TSTRIDE
                           + (uu + qp) * 16 + (quad & 1) * 8);
            }
            #pragma unroll
            for (int r = 0; r < 4; r++) {
                const int g = wave * 32 + gt * 16 + quad * 4 + r;
                float c1x = acc[0][gt][0][r];
                float c1y = acc[0][gt][1][r];
                float c1z = acc[0][gt][2][r];
                float c2x = acc[1][gt][0][r];
                float c2y = acc[1][gt][1][r];
                float c2z = acc[1][gt][2][r];
                float d0 = m1v[0]*c1x + m1v[1]*c1y + m1v[2]*c1z;
                float d1 = m1v[3]*c1x + m1v[4]*c1y + m1v[5]*c1z;
                float d2 = m1v[6]*c1x + m1v[7]*c1y + m1v[8]*c1z;
                float e0 = m2v[0]*c2x + m2v[1]*c2y + m2v[2]*c2z;
                float e1 = m2v[3]*c2x + m2v[4]*c2y + m2v[5]*c2z;
                float e2 = m2v[6]*c2x + m2v[7]*c2y + m2v[8]*c2z;
                float v0 = e1 * d2 - e2 * d1;
                float v1 = e2 * d0 - e0 * d2;
                float v2 = e0 * d1 - e1 * d0;
                ob[(size_t)(g * 3 + 0) * N_] = bf2f(rx[0][r]) + v0;
                ob[(size_t)(g * 3 + 1) * N_] = bf2f(rx[1][r]) + v1;
                ob[(size_t)(g * 3 + 2) * N_] = bf2f(rx[2][r]) + v2;
            }
        }
        task = next;
    }
}

extern "C" void kernel_launch(void* const* d_in, const int* in_sizes, int n_in,
                              void* d_out, int out_size, void* d_ws, size_t ws_size,
                              hipStream_t stream) {
    const float* x  = (const float*)d_in[0];
    const float* M1 = (const float*)d_in[1];
    const float* M2 = (const float*)d_in[2];
    const float* W1 = (const float*)d_in[3];
    const float* W2 = (const float*)d_in[4];
    float* out = (float*)d_out;
    unsigned short* Wb = (unsigned short*)d_ws;   // 256 KiB

    wconv_kernel<<<64, 256, 0, stream>>>(W1, W2, Wb);
    lie_fused_kernel<<<GRID, THREADS, 0, stream>>>(x, M1, M2, Wb, out);
}